// Round 12
// baseline (655.535 us; speedup 1.0000x reference)
//
#include <hip/hip_runtime.h>
#include <cstddef>

// WITRAN 2D PSGMU encoder, MI355X — v15 (resubmit; R11 was a broker timeout,
// kernel never ran): v14 base (579us: launch-per-step, triangle grid,
// split-K 12 waves, W reg-prefetch, fp16 h carry) + three refinements:
//  1. PAIR-XCD swizzle (s>=22): XCD = (mc>>1)&7 -> chunk pairs {2x,2x+1}
//     own one XCD (32 blocks = its 32 CUs). h_row always XCD-local;
//     h_col cross-XCD only for even chunks (was: all boundaries cross).
//  2. DIRECT-X: x fragments built in step_k from inp (2x f32x4 + cvt, same
//     (_Float16) rounding as prep -> bit-identical); xall buffer and its
//     prep pass deleted (prep 10848 -> 4032 blocks).
//  3. Gt stride 112 (112%32=16): exchange buffer 2-way banks on both sides.
// Rejected on paper: all-gates-per-wave repack (split-K still needs the
// cross-wave sum -> same exchange cost, +33% MFMA). 2-step fusion (per-CU
// W re-stream = v9/v10's 10.9us/step floor).
// Counter-refuted: v6 flag-sync, v7 2-blk/CU, v9/v10 persistent, v12 gl_lds.
// absmax must stay exactly 9.766e-4.

namespace {
constexpr int H_   = 256;
constexpr int R_   = 24;
constexpr int LOR_ = 48;
constexpr int L_   = 71;
constexpr int N_   = 768;
constexpr int KH_  = 512;
constexpr int KT_  = 544;
constexpr int AST_ = 552;   // LDS h-tile stride (elems)
constexpr int GST_ = 112;   // Gt stride (f32): %32==16 -> 2-way banks
}

typedef __attribute__((ext_vector_type(8))) _Float16       f16x8;
typedef __attribute__((ext_vector_type(8))) unsigned short u16x8;
typedef __attribute__((ext_vector_type(4))) float          f32x4;

__device__ __forceinline__ float fsig(float x)  { return 1.f / (1.f + __expf(-x)); }
__device__ __forceinline__ float ftanhf(float x){ float e = __expf(2.f * x); return 1.f - 2.f / (e + 1.f); }

// ---------------------------------------------------------------------------
// Fused prep: Wfrag build + BOTH h buffers zeroed (xall deleted — direct-x).
// Wfrag[((kc*96 + lt)*64 + lane)*8 + j8]; lt=kt*6+g; col j=g*256+kt*16+kl
// ---------------------------------------------------------------------------
__global__ __launch_bounds__(256) void prep_all(const float* __restrict__ W,
                                                _Float16* __restrict__ Wfrag,
                                                unsigned long long* __restrict__ zb) {
    const int bx = blockIdx.x;
    const int t  = threadIdx.x;
    if (bx < 3264) {                                 // W -> fragment fp16
        int o = bx * 256 + t;                        // < 835,584
        int j8   = o & 7;
        int lane = (o >> 3) & 63;
        int rest = o >> 9;
        int lt   = rest % 96;
        int kc   = rest / 96;                        // < 17
        int n0 = lane & 15, quad = lane >> 4;
        int lg  = lt * 16 + n0;
        int kt  = lg / 96;
        int rem = lg % 96;
        int g  = rem >> 4, kl = rem & 15;
        int j  = g * 256 + kt * 16 + kl;
        int kg = kc * 32 + quad * 8 + j8;
        Wfrag[o] = (_Float16)W[j * KT_ + kg];
    } else {                                         // zero hb0+hb1 (196,608 u64)
        zb[(bx - 3264) * 256 + t] = 0ull;
    }
}

// ---------------------------------------------------------------------------
// One step. Grid = nmc*16 blocks. 768 thr = 12 waves, 3 waves/SIMD.
// Waves 0-5: gate g=wv, kc 0-8.  Waves 6-11: gate g=wv-6, kc 9-16 (incl x).
// ---------------------------------------------------------------------------
__global__ __launch_bounds__(768, 3) void step_k(
    const _Float16* __restrict__ Wfrag,
    const float*    __restrict__ inp,
    const _Float16* __restrict__ hbc,
    _Float16*       __restrict__ hbn,
    const float* __restrict__ Bp,
    float* __restrict__ out0, float* __restrict__ out1, float* __restrict__ out2,
    int s)
{
    __shared__ unsigned short As[48 * AST_];   // h tile 48x512 (stride 552)
    __shared__ float Gt[2][48][GST_];          // split-K partial gates

    const int t    = threadIdx.x;
    const int wv   = t >> 6;                   // 0..11
    const int lane = t & 63;
    const int n0   = lane & 15;
    const int quad = lane >> 4;

    // block decode: pair-XCD swizzle on full-grid steps (s>=22)
    int kt, mc;
    if (s >= 22) {
        int x = blockIdx.x & 7;                // XCD (round-robin bid%8)
        mc = (x << 1) | ((blockIdx.x >> 3) & 1);
        kt = blockIdx.x >> 4;
    } else {
        kt = blockIdx.x & 15; mc = blockIdx.x >> 4;
    }

    const bool hi = (wv >= 6);
    const int  g  = hi ? wv - 6 : wv;

    // ---- W prefetch (this wave's kc range) ----------------------------------
    f16x8 bfr[9];
    f16x8 xf[3];
    if (!hi) {
#pragma unroll
        for (int i = 0; i < 9; ++i)
            bfr[i] = *(const f16x8*)(const void*)(
                Wfrag + ((size_t)(i * 96 + kt * 6 + g) * 64 + lane) * 8);
    } else {
#pragma unroll
        for (int i = 0; i < 8; ++i)
            bfr[i] = *(const f16x8*)(const void*)(
                Wfrag + ((size_t)((9 + i) * 96 + kt * 6 + g) * 64 + lane) * 8);
        // direct-x fragments: per-lane row n, cols quad*8..+8 from inp (fp32)
#pragma unroll
        for (int mt = 0; mt < 3; ++mt) {
            int n = mc * 48 + mt * 16 + n0;
            int r = n >> 5, b = n & 31;
            int l = s - r;
            if (l >= 0 && l < LOR_) {
                const float* xp = inp + (((size_t)b * LOR_ + l) * R_ + r) * 32 + quad * 8;
                f32x4 lo = *(const f32x4*)(const void*)(xp);
                f32x4 hh = *(const f32x4*)(const void*)(xp + 4);
                f16x8 v;
#pragma unroll
                for (int j = 0; j < 4; ++j) { v[j] = (_Float16)lo[j]; v[4 + j] = (_Float16)hh[j]; }
                xf[mt] = v;
            } else {
                xf[mt] = (f16x8){0, 0, 0, 0, 0, 0, 0, 0};
            }
        }
    }

    // ---- early Bp loads -----------------------------------------------------
    const int mm = t >> 4;                     // update row (0..47)
    const int kp = t & 15;
    const int n  = mc * 48 + mm;
    const int k  = kt * 16 + kp;
    float bp[6];
    if (s < R_) {
#pragma unroll
        for (int gg = 0; gg < 6; ++gg)
            bp[gg] = Bp[gg * 256 + k];
    }

    // ---- stage h (48x512) into LDS ------------------------------------------
#pragma unroll
    for (int it = 0; it < 4; ++it) {
        int q   = it * 768 + t;                // < 3072
        int row = q >> 6;
        int col = (q & 63) * 8;
        *(u16x8*)(void*)(&As[row * AST_ + col]) =
            *(const u16x8*)(const void*)((const unsigned short*)hbc +
                                         (size_t)(mc * 48 + row) * KH_ + col);
    }
    __syncthreads();

    // ---- GEMM: split-K halves -----------------------------------------------
    f32x4 acc[3];
#pragma unroll
    for (int mt = 0; mt < 3; ++mt) acc[mt] = (f32x4){0.f, 0.f, 0.f, 0.f};

    if (!hi) {
#pragma unroll
        for (int i = 0; i < 9; ++i) {
            f16x8 a[3];
#pragma unroll
            for (int mt = 0; mt < 3; ++mt)
                a[mt] = *(const f16x8*)(const void*)(
                    &As[(mt * 16 + n0) * AST_ + i * 32 + quad * 8]);
#pragma unroll
            for (int mt = 0; mt < 3; ++mt)
                acc[mt] = __builtin_amdgcn_mfma_f32_16x16x32_f16(a[mt], bfr[i], acc[mt], 0, 0, 0);
        }
    } else {
#pragma unroll
        for (int i = 0; i < 7; ++i) {
            f16x8 a[3];
#pragma unroll
            for (int mt = 0; mt < 3; ++mt)
                a[mt] = *(const f16x8*)(const void*)(
                    &As[(mt * 16 + n0) * AST_ + (9 + i) * 32 + quad * 8]);
#pragma unroll
            for (int mt = 0; mt < 3; ++mt)
                acc[mt] = __builtin_amdgcn_mfma_f32_16x16x32_f16(a[mt], bfr[i], acc[mt], 0, 0, 0);
        }
#pragma unroll
        for (int mt = 0; mt < 3; ++mt)
            acc[mt] = __builtin_amdgcn_mfma_f32_16x16x32_f16(xf[mt], bfr[7], acc[mt], 0, 0, 0);
    }

    // D layout: col = lane&15 (gate col), row = quad*4 + reg (m)
    {
        float (*gt)[GST_] = Gt[hi ? 1 : 0];
#pragma unroll
        for (int mt = 0; mt < 3; ++mt)
#pragma unroll
            for (int reg = 0; reg < 4; ++reg)
                gt[mt * 16 + quad * 4 + reg][g * 16 + n0] = acc[mt][reg];
    }
    __syncthreads();

    // ---- fused update: thread = 1 m-row x 1 k -------------------------------
    {
        const int r  = n >> 5, b = n & 31;
        const bool useb = (r <= s) && (s < R_);

        float gv[6];
#pragma unroll
        for (int gg = 0; gg < 6; ++gg) {
            float v = Gt[0][mm][gg * 16 + kp] + Gt[1][mm][gg * 16 + kp];
            gv[gg] = useb ? (v + bp[gg]) : v;
        }

        float hro = (float)*(const _Float16*)(const void*)&As[mm * AST_ + k];
        float hco = (float)*(const _Float16*)(const void*)&As[mm * AST_ + 256 + k];

        float ur = fsig(gv[0]), oR = fsig(gv[1]);
        float uc = fsig(gv[2]), oc = fsig(gv[3]);
        float ir = ftanhf(gv[4]), ic = ftanhf(gv[5]);
        float hrv = ftanhf((1.f - ur) * hro + ur * ir) * oR;
        float hcv = ftanhf((1.f - uc) * hco + uc * ic) * oc;

        float* o0 = out0 + ((size_t)n * L_ + s) * 512;
        __builtin_nontemporal_store(hrv, o0 + k);
        __builtin_nontemporal_store(hcv, o0 + 256 + k);

        int n2 = n + 32; if (n2 >= N_) n2 -= N_;
        hbn[(size_t)n  * KH_ + k]       = (_Float16)hrv;
        hbn[(size_t)n2 * KH_ + 256 + k] = (_Float16)hcv;

        if (s >= LOR_ - 1 && r == s - (LOR_ - 1))
            __builtin_nontemporal_store(hrv, out2 + (size_t)(b * R_ + r) * H_ + k);
        if (r == R_ - 1 && s >= R_ - 1)
            __builtin_nontemporal_store(hcv, out1 + (size_t)(b * LOR_ + (s - (R_ - 1))) * H_ + k);
    }
}

// ---------------------------------------------------------------------------
extern "C" void kernel_launch(void* const* d_in, const int* in_sizes, int n_in,
                              void* d_out, int out_size, void* d_ws, size_t ws_size,
                              hipStream_t stream) {
    const float* inp = (const float*)d_in[0];
    const float* W   = (const float*)d_in[1];
    const float* Bp  = (const float*)d_in[2];

    float* out0 = (float*)d_out;
    float* out1 = out0 + (size_t)N_ * L_ * 512;
    float* out2 = out1 + (size_t)32 * LOR_ * H_;

    char* ws = (char*)d_ws;
    _Float16* Wfrag = (_Float16*)(ws);                 // 1,671,168 B
    _Float16* hb0   = (_Float16*)(ws + 1671168);       //   786,432 B
    _Float16* hb1   = (_Float16*)(ws + 2457600);       //   786,432 B (contiguous)

    prep_all<<<4032, 256, 0, stream>>>(W, Wfrag, (unsigned long long*)hb0);

    for (int s = 0; s < L_; ++s) {
        const _Float16* hbc = (s & 1) ? hb1 : hb0;
        _Float16*       hbn = (s & 1) ? hb0 : hb1;
        int act = (s < 23 ? s : 23) + 1;               // active r-groups
        int nmc = (32 * act + 47) / 48;                // active 48-row chunks
        step_k<<<nmc * 16, 768, 0, stream>>>(Wfrag, inp, hbc, hbn,
                                             Bp, out0, out1, out2, s);
    }
}